// Round 4
// baseline (303.679 us; speedup 1.0000x reference)
//
#include <hip/hip_runtime.h>

// TAdaConv2d via bf16 MFMA implicit GEMM (raw-short bf16).
//   prep_w: W[co][ci][tap] fp32 -> wb[tap][co][ci] bf16 (plain, for register A-frags)
//   prep_x: x NCHW fp32 * alpha -> xhat[bt][y][w][slot*8+ci&7] bf16, slot=(ci>>3)^(w&7)
//   conv2 : block=(bt, 4-row tile); wave = 32co x 32w; A-frags in registers (36x16B);
//           one barrier; B-frags via swizzled LDS ds_read_b128 (conflict-free).

#define CIN  64
#define COUT 64
#define TT   16
#define BB   8
#define HH   64
#define WW   64

typedef __attribute__((ext_vector_type(8))) short bf16x8;
typedef __attribute__((ext_vector_type(4))) float f32x4;

__device__ __forceinline__ unsigned int f2bf(float f) {
    union { float f; unsigned u; } v; v.f = f;
    return (v.u + 0x7FFF + ((v.u >> 16) & 1)) >> 16;   // RNE fp32->bf16 (low 16 bits)
}

// ---------------- prep_x: transpose + alpha-fold + bf16 + swizzle ----------------
// block = one (bt, h) row-plane: [ci=64][w=64] fp32 -> xhat row [w][slot][8] bf16
__global__ __launch_bounds__(256) void prep_x(const float* __restrict__ x,
                                              const float* __restrict__ alpha,
                                              int4* __restrict__ xh) {
    __shared__ float ls[64 * 67];   // [w][ci], stride 67: phase1 & phase2 ~2-way (free)
    const int blk = blockIdx.x;     // bt*64 + h
    const int h   = blk & 63;
    const int bt  = blk >> 6;
    const int t   = bt & 15;
    const int b   = bt >> 4;
    const int tid = threadIdx.x;

#pragma unroll
    for (int it = 0; it < 4; ++it) {
        int idx4 = tid + it * 256;          // 0..1023
        int ci   = idx4 >> 4;
        int w4   = (idx4 & 15) * 4;
        float a  = alpha[(b * CIN + ci) * TT + t];
        const float* gp = x + (((b * CIN + ci) * TT + t) * HH + h) * WW + w4;
        float4 v = *(const float4*)gp;
        ls[(w4 + 0) * 67 + ci] = v.x * a;
        ls[(w4 + 1) * 67 + ci] = v.y * a;
        ls[(w4 + 2) * 67 + ci] = v.z * a;
        ls[(w4 + 3) * 67 + ci] = v.w * a;
    }
    __syncthreads();

#pragma unroll
    for (int it = 0; it < 2; ++it) {
        int tau  = tid + it * 256;          // 0..511
        int w    = tau >> 3;
        int slot = tau & 7;
        int g    = slot ^ (w & 7);
        const float* p = &ls[w * 67 + g * 8];
        int4 o;
        o.x = (int)(f2bf(p[0]) | (f2bf(p[1]) << 16));
        o.y = (int)(f2bf(p[2]) | (f2bf(p[3]) << 16));
        o.z = (int)(f2bf(p[4]) | (f2bf(p[5]) << 16));
        o.w = (int)(f2bf(p[6]) | (f2bf(p[7]) << 16));
        xh[((bt * 64 + h) * 64 + w) * 8 + slot] = o;
    }
}

// ---------------- prep_w: weight -> wb[tap][co][ci] bf16 (plain) ----------------
__global__ __launch_bounds__(256) void prep_w(const float* __restrict__ wgt,
                                              unsigned short* __restrict__ wb) {
    int idx = blockIdx.x * 256 + threadIdx.x;   // over co*ci*tap = 36864
    if (idx < COUT * CIN * 9) {
        int co  = idx / (CIN * 9);
        int r   = idx - co * (CIN * 9);
        int ci  = r / 9;
        int tap = r - ci * 9;
        wb[(tap * COUT + co) * CIN + ci] = (unsigned short)f2bf(wgt[idx]);
    }
}

// ---------------- conv2: MFMA implicit GEMM, A in registers ----------------
// block: (bt, ytile of 4 rows). 4 waves = (mh 0/1) x (nh 0/1): 32co x 32w each.
__global__ __launch_bounds__(256, 2) void conv2(const short* __restrict__ xh,
                                                const short* __restrict__ wb,
                                                const float* __restrict__ bias,
                                                float* __restrict__ out) {
    __shared__ __align__(16) short xs[6 * 4224];   // 6 rows x (66 px x 64 ci) = 49.5 KB

    const int blk   = blockIdx.x;
    const int ytile = blk & 15;
    const int bt    = blk >> 4;
    const int t     = bt & 15;
    const int b     = bt >> 4;
    const int y0    = ytile * 4;
    const int tid   = threadIdx.x;
    const int wave  = tid >> 6;
    const int lane  = tid & 63;
    const int lane15 = lane & 15;
    const int laneh  = lane >> 4;
    const int mh    = wave >> 1;
    const int nh    = wave & 1;

    // ---- stage 6 x-rows (gy = y0-1 .. y0+4), zero-fill halo cols + OOB rows ----
    for (int tsk = tid; tsk < 6 * 528; tsk += 256) {
        int r  = tsk / 528;
        int i  = tsk - r * 528;
        int gy = y0 - 1 + r;
        int4 v = {0, 0, 0, 0};
        if ((unsigned)gy < (unsigned)HH) {
            int j = i - 8;                       // skip 8-int4 left halo col
            if ((unsigned)j < 512u)
                v = ((const int4*)xh)[(bt * 64 + gy) * 512 + j];
        }
        ((int4*)xs)[r * 528 + i] = v;
    }

    // ---- load all 36 A-frags (2 co-tiles x 18 k-steps) into registers ----
    bf16x8 af[36];
#pragma unroll
    for (int s = 0; s < 18; ++s) {
        const int tap = s >> 1;
        const int kc  = s & 1;
        const int ci0 = kc * 32 + laneh * 8;
#pragma unroll
        for (int mi = 0; mi < 2; ++mi) {
            int co = mh * 32 + mi * 16 + lane15;
            af[s * 2 + mi] = *(const bf16x8*)(wb + (tap * COUT + co) * CIN + ci0);
        }
    }
    __syncthreads();

    for (int y = 0; y < 4; ++y) {
        f32x4 acc[2][2] = {};
#pragma unroll
        for (int s = 0; s < 18; ++s) {
            const int tap = s >> 1;
            const int kc  = s & 1;
            const int ky  = tap / 3;
            const int dx  = (tap - 3 * ky) - 1;
            const short* xrow = xs + (y + ky) * 4224;
            bf16x8 bfr[2];
#pragma unroll
            for (int nt = 0; nt < 2; ++nt) {
                int w    = nh * 32 + nt * 16 + lane15;
                int wx   = w + dx;                       // -1..64 -> halo zeros
                int slot = (kc * 4 + laneh) ^ (wx & 7);
                bfr[nt] = *(const bf16x8*)(xrow + (wx + 1) * 64 + slot * 8);
            }
#pragma unroll
            for (int mi = 0; mi < 2; ++mi)
#pragma unroll
                for (int nt = 0; nt < 2; ++nt)
                    acc[mi][nt] = __builtin_amdgcn_mfma_f32_16x16x32_bf16(
                        af[s * 2 + mi], bfr[nt], acc[mi][nt], 0, 0, 0);
        }
        // ---- epilogue row y0+y ----
        const int gy = y0 + y;
#pragma unroll
        for (int mi = 0; mi < 2; ++mi) {
#pragma unroll
            for (int r = 0; r < 4; ++r) {
                int co = mh * 32 + mi * 16 + laneh * 4 + r;
                float bv = bias[co];
                float* op = out + (((b * COUT + co) * TT + t) * HH + gy) * WW;
#pragma unroll
                for (int nt = 0; nt < 2; ++nt)
                    op[nh * 32 + nt * 16 + lane15] = acc[mi][nt][r] + bv;
            }
        }
    }
}

extern "C" void kernel_launch(void* const* d_in, const int* in_sizes, int n_in,
                              void* d_out, int out_size, void* d_ws, size_t ws_size,
                              hipStream_t stream) {
    const float* x      = (const float*)d_in[0];
    const float* alpha  = (const float*)d_in[1];
    const float* weight = (const float*)d_in[2];
    const float* bias   = (const float*)d_in[3];
    float* out          = (float*)d_out;

    // workspace: [0,128K): wb (73.7 KB used); [128K, +67.1MB): xhat
    unsigned short* wb = (unsigned short*)d_ws;
    short* xhat = (short*)((char*)d_ws + (128 << 10));

    hipLaunchKernelGGL(prep_w, dim3(144), dim3(256), 0, stream, weight, wb);
    hipLaunchKernelGGL(prep_x, dim3(BB * TT * HH), dim3(256), 0, stream,
                       x, alpha, (int4*)xhat);
    hipLaunchKernelGGL(conv2, dim3(BB * TT * (HH / 4)), dim3(256), 0, stream,
                       xhat, (const short*)wb, bias, out);
}